// Round 16
// baseline (256.850 us; speedup 1.0000x reference)
//
#include <hip/hip_runtime.h>
#include <hip/hip_bf16.h>
#include <hip/hip_fp16.h>

// ---------------------------------------------------------------------------
// 2-layer GAT (PyG GATConv semantics).
// Round 27 = r26 (248.3us) + ONE coherent delta: pre-packed split-bf16 A.
//  - pack_w12 also packs x -> xh/xl (grid-stride; conversions paid once)
//  - gemm_body stages A by pure 16B copies (no f32->bf16 cvt in the K-loop;
//    bit-identical numerics: pre-pack applies the same RNE hi/lo split)
//  - agg1 mode-0 epilogue writes ELU output directly as split-bf16
//    (agg_hi/agg_lo) so gemm2's A is pre-packed too; mode-1 f32 unchanged.
// Kept byte-identical: aggregate inner loop (r26 saddr+exp2 form, 48.5us
// plateau), gemm1+scatter fused dispatch, MFMA core, final head.
// ---------------------------------------------------------------------------

#define HEADS 4
#define CDIM 64
#define HC 256   // HEADS*CDIM
#define ELLW 96  // ELL row stride (ints)
#define CNTS 16  // cnt stride in ints (64B line per counter)
#define NCHUNK 320  // edge chunks; scatter blocks = NCHUNK*8
#define LOG2E 1.44269504088896f
#define PACKB 1280  // pack grid blocks

typedef __attribute__((ext_vector_type(8))) short bf16x8;   // 8 bf16 = 4 VGPR
typedef __attribute__((ext_vector_type(4))) float f32x4;    // MFMA acc

__device__ __forceinline__ short f32_to_bf16_rne(float v) {
  unsigned u = __float_as_uint(v);
  unsigned r = (u + 0x7FFFu + ((u >> 16) & 1u)) >> 16;
  return (short)r;
}
__device__ __forceinline__ float bf16_bits_to_f32(short s) {
  return __uint_as_float(((unsigned)(unsigned short)s) << 16);
}

// acc_lo += f16lo(reg)*ex ; acc_hi += f16hi(reg)*ex   (f32 accumulate)
__device__ __forceinline__ void fma_mix2(float& alo, float& ahi,
                                         unsigned reg, float ex) {
  asm("v_fma_mix_f32 %0, %2, %3, %0 op_sel:[0,0,0] op_sel_hi:[1,0,0]\n\t"
      "v_fma_mix_f32 %1, %2, %3, %1 op_sel:[1,0,0] op_sel_hi:[1,0,0]"
      : "+v"(alo), "+v"(ahi)
      : "v"(reg), "v"(ex));
}
__device__ __forceinline__ void fma_mix8(float ex, const uint4& u, float* acc) {
  fma_mix2(acc[0], acc[1], u.x, ex);
  fma_mix2(acc[2], acc[3], u.y, ex);
  fma_mix2(acc[4], acc[5], u.z, ex);
  fma_mix2(acc[6], acc[7], u.w, ex);
}

// --- weight pack + x pack (grid-stride) + cnt-line zeroing, one launch -----
__global__ __launch_bounds__(256) void pack_w12_kernel(
    const float* __restrict__ W1, short* __restrict__ W1h,
    short* __restrict__ W1l, const float* __restrict__ W2,
    short* __restrict__ W2h, short* __restrict__ W2l,
    const float* __restrict__ x, short* __restrict__ xh,
    short* __restrict__ xl, int NX,   // NX = N*128
    int* __restrict__ cnt, int N) {
  const int i = blockIdx.x * 256 + threadIdx.x;
  if (i < N) cnt[i * CNTS] = 0;   // one counter per 64B line
  // x -> split-bf16 (same RNE hi/lo the gemm staging used to apply)
  for (int k = i; k < NX; k += PACKB * 256) {
    const float v = x[k];
    const short hi = f32_to_bf16_rne(v);
    xh[k] = hi;
    xl[k] = f32_to_bf16_rne(v - bf16_bits_to_f32(hi));
  }
  if (i < 128 * 256) {
    const int k = i >> 8, n = i & 255;
    const float v = W1[i];
    const short hi = f32_to_bf16_rne(v);
    W1h[n * 128 + k] = hi;
    W1l[n * 128 + k] = f32_to_bf16_rne(v - bf16_bits_to_f32(hi));
  } else if (i < 384 * 256) {
    const int j = i - 128 * 256;
    const int k = j >> 8, n = j & 255;
    const float v = W2[j];
    const short hi = f32_to_bf16_rne(v);
    W2h[n * 256 + k] = hi;
    W2l[n * 256 + k] = f32_to_bf16_rne(v - bf16_bits_to_f32(hi));
  }
}

// ---------------- split-bf16 MFMA GEMM body: h = A[M,K] @ W[K,256] ---------
// block = 256 thr (4 waves); wave = head. A arrives PRE-PACKED (Ah/Al) ->
// staging is pure 16B copies through LDS (no cvt in K-loop). Epilogue stores
// attention scores pre-scaled by LOG2E.
__device__ __forceinline__ void gemm_body(
    short* As_hi, short* As_lo,
    const short* __restrict__ Ah, const short* __restrict__ Al,
    const short* __restrict__ Wt_hi, const short* __restrict__ Wt_lo,
    __half* __restrict__ h16,
    const float* __restrict__ att_s, const float* __restrict__ att_d,
    float* __restrict__ a_s, float* __restrict__ a_d, int M, int K, int bid) {
  const int t = threadIdx.x;
  const int wave = t >> 6;         // == head
  const int lane = t & 63;
  const int quad = lane >> 4;
  const int m16 = lane & 15;
  const int row0 = bid * 64;
  const int col0 = wave * 64;
  const int head = wave;

  f32x4 acc[4][4] = {};  // [mt][nt]

  for (int k0 = 0; k0 < K; k0 += 32) {
    if (k0) __syncthreads();
    {
      const int r = t >> 2, seg = t & 3;   // single-pass staging: 64x32
      const int gr = row0 + r;
      bf16x8 h8 = {0, 0, 0, 0, 0, 0, 0, 0};
      bf16x8 l8 = {0, 0, 0, 0, 0, 0, 0, 0};
      if (gr < M) {
        const size_t off = (size_t)gr * K + k0 + seg * 8;
        h8 = *(const bf16x8*)(Ah + off);
        l8 = *(const bf16x8*)(Al + off);
      }
      *(bf16x8*)(As_hi + r * 32 + seg * 8) = h8;
      *(bf16x8*)(As_lo + r * 32 + seg * 8) = l8;
    }
    bf16x8 b_hi[4], b_lo[4];
#pragma unroll
    for (int nt = 0; nt < 4; ++nt) {
      const size_t off = (size_t)(col0 + nt * 16 + m16) * K + k0 + quad * 8;
      b_hi[nt] = *(const bf16x8*)(Wt_hi + off);
      b_lo[nt] = *(const bf16x8*)(Wt_lo + off);
    }
    __syncthreads();
    bf16x8 a_hi[4], a_lo[4];
#pragma unroll
    for (int mt = 0; mt < 4; ++mt) {
      const int off = (mt * 16 + m16) * 32 + quad * 8;
      a_hi[mt] = *(const bf16x8*)(As_hi + off);
      a_lo[mt] = *(const bf16x8*)(As_lo + off);
    }
#pragma unroll
    for (int mt = 0; mt < 4; ++mt)
#pragma unroll
      for (int nt = 0; nt < 4; ++nt) {
        acc[mt][nt] = __builtin_amdgcn_mfma_f32_16x16x32_bf16(
            a_hi[mt], b_hi[nt], acc[mt][nt], 0, 0, 0);
        acc[mt][nt] = __builtin_amdgcn_mfma_f32_16x16x32_bf16(
            a_hi[mt], b_lo[nt], acc[mt][nt], 0, 0, 0);
        acc[mt][nt] = __builtin_amdgcn_mfma_f32_16x16x32_bf16(
            a_lo[mt], b_hi[nt], acc[mt][nt], 0, 0, 0);
      }
  }
  float sa[4], da[4];
#pragma unroll
  for (int nt = 0; nt < 4; ++nt) {
    sa[nt] = att_s[col0 + nt * 16 + m16];
    da[nt] = att_d[col0 + nt * 16 + m16];
  }
#pragma unroll
  for (int mt = 0; mt < 4; ++mt)
#pragma unroll
    for (int r = 0; r < 4; ++r) {
      const int gr = row0 + mt * 16 + quad * 4 + r;
      float ps = acc[mt][0][r] * sa[0] + acc[mt][1][r] * sa[1] +
                 acc[mt][2][r] * sa[2] + acc[mt][3][r] * sa[3];
      float pd = acc[mt][0][r] * da[0] + acc[mt][1][r] * da[1] +
                 acc[mt][2][r] * da[2] + acc[mt][3][r] * da[3];
#pragma unroll
      for (int off = 1; off <= 8; off <<= 1) {
        ps += __shfl_xor(ps, off);
        pd += __shfl_xor(pd, off);
      }
      if (gr < M) {
        if (m16 == 0) {
          a_s[gr * HEADS + head] = ps * LOG2E;   // pre-scaled for exp2
          a_d[gr * HEADS + head] = pd * LOG2E;
        }
#pragma unroll
        for (int nt = 0; nt < 4; ++nt)
          h16[(size_t)gr * HC + col0 + nt * 16 + m16] =
              __float2half(acc[mt][nt][r]);
      }
    }
}

// plain GEMM kernel (layer 2)
__global__ __launch_bounds__(256) void gemm_mfma_split(
    const short* __restrict__ Ah, const short* __restrict__ Al,
    const short* __restrict__ Wt_hi, const short* __restrict__ Wt_lo,
    __half* __restrict__ h16,
    const float* __restrict__ att_s, const float* __restrict__ att_d,
    float* __restrict__ a_s, float* __restrict__ a_d, int M, int K) {
  __shared__ alignas(16) short As_hi[64 * 32];
  __shared__ alignas(16) short As_lo[64 * 32];
  gemm_body(As_hi, As_lo, Ah, Al, Wt_hi, Wt_lo, h16, att_s, att_d, a_s, a_d,
            M, K, blockIdx.x);
}

// ====== fused gemm1 + XCD-bucketed ELL scatter (independent ops) ===========
__global__ __launch_bounds__(256) void gemm1_scatter_fused(
    const short* __restrict__ Ah, const short* __restrict__ Al,
    const short* __restrict__ Wt_hi, const short* __restrict__ Wt_lo,
    __half* __restrict__ h16,
    const float* __restrict__ att_s, const float* __restrict__ att_d,
    float* __restrict__ a_s, float* __restrict__ a_d, int M, int K,
    int gblocks, const int* __restrict__ src, const int* __restrict__ dst,
    int* __restrict__ cnt, int* __restrict__ ell, int E_raw, int Etot,
    int chunk_sz) {
  __shared__ alignas(16) short As_hi[64 * 32];
  __shared__ alignas(16) short As_lo[64 * 32];
  const int bx = blockIdx.x;
  if (bx < gblocks) {
    gemm_body(As_hi, As_lo, Ah, Al, Wt_hi, Wt_lo, h16, att_s, att_d, a_s, a_d,
              M, K, bx);
  } else {
    const int g = bx & 7;
    const int e0 = ((bx - gblocks) >> 3) * chunk_sz;
    int e1 = e0 + chunk_sz;
    if (e1 > Etot) e1 = Etot;
    for (int e = e0 + threadIdx.x; e < e1; e += 256) {
      const int d = (e < E_raw) ? dst[e] : (e - E_raw);
      if (((d >> 8) & 7) != g) continue;
      const int s = (e < E_raw) ? src[e] : (e - E_raw);
      const int pos = atomicAdd(&cnt[d * CNTS], 1);
      if (pos < ELLW) ell[d * ELLW + pos] = s;  // P(overflow) ~ 7e-18
    }
  }
}

// ================= fused softmax + aggregation (f16 gather) ================
// (r26 inner loop, byte-identical) head-affine blocks, wave = node.
// mode 0: ELU(v + b) -> SPLIT-BF16 (agg_hi/agg_lo) for gemm2's pre-packed A.
// mode 1: v -> f32 outf (for final head).
__global__ __launch_bounds__(256) void gat_aggregate_kernel(
    const int* __restrict__ cnt, const int* __restrict__ ell,
    const __half* __restrict__ h16, const float* __restrict__ a_s,
    const float* __restrict__ a_d, const float* __restrict__ b,
    short* __restrict__ agg_hi, short* __restrict__ agg_lo,
    float* __restrict__ outf, int mode) {
  const int bid = blockIdx.x;
  const int hd = bid & 3;
  const int n = (bid >> 2) * 4 + (threadIdx.x >> 6);
  const int lane = threadIdx.x & 63;
  const int q = lane >> 3;
  const int oc = lane & 7;
  const float ad = a_d[n * HEADS + hd];
  const int deg = cnt[n * CNTS];
  const int* __restrict__ row = ell + n * ELLW;
  const float* __restrict__ asp = a_s;                 // uniform base
  const unsigned hdu = (unsigned)hd;
  const char* __restrict__ hby = (const char*)h16;     // uniform base
  const unsigned cof = (unsigned)(hd * 128 + oc * 16); // per-lane voff const
  float acc[8] = {0.f, 0.f, 0.f, 0.f, 0.f, 0.f, 0.f, 0.f};
  float den = 0.f;
  int i = q;
  for (; i + 24 < deg; i += 32) {
    const unsigned s0 = (unsigned)row[i];
    const unsigned s1 = (unsigned)row[i + 8];
    const unsigned s2 = (unsigned)row[i + 16];
    const unsigned s3 = (unsigned)row[i + 24];
    const float as0 = asp[s0 * 4u + hdu];
    const float as1 = asp[s1 * 4u + hdu];
    const float as2 = asp[s2 * 4u + hdu];
    const float as3 = asp[s3 * 4u + hdu];
    const uint4 u0 = *(const uint4*)(hby + (size_t)((s0 << 9) + cof));
    const uint4 u1 = *(const uint4*)(hby + (size_t)((s1 << 9) + cof));
    const uint4 u2 = *(const uint4*)(hby + (size_t)((s2 << 9) + cof));
    const uint4 u3 = *(const uint4*)(hby + (size_t)((s3 << 9) + cof));
    float a0 = as0 + ad; a0 = fmaxf(a0, 0.2f * a0);
    float a1 = as1 + ad; a1 = fmaxf(a1, 0.2f * a1);
    float a2 = as2 + ad; a2 = fmaxf(a2, 0.2f * a2);
    float a3 = as3 + ad; a3 = fmaxf(a3, 0.2f * a3);
    const float e0 = exp2f(a0);
    const float e1 = exp2f(a1);
    const float e2 = exp2f(a2);
    const float e3 = exp2f(a3);
    den += e0 + e1 + e2 + e3;
    fma_mix8(e0, u0, acc);
    fma_mix8(e1, u1, acc);
    fma_mix8(e2, u2, acc);
    fma_mix8(e3, u3, acc);
  }
  for (; i + 8 < deg; i += 16) {
    const unsigned s0 = (unsigned)row[i];
    const unsigned s1 = (unsigned)row[i + 8];
    const float as0 = asp[s0 * 4u + hdu];
    const float as1 = asp[s1 * 4u + hdu];
    const uint4 u0 = *(const uint4*)(hby + (size_t)((s0 << 9) + cof));
    const uint4 u1 = *(const uint4*)(hby + (size_t)((s1 << 9) + cof));
    float a0 = as0 + ad; a0 = fmaxf(a0, 0.2f * a0);
    float a1 = as1 + ad; a1 = fmaxf(a1, 0.2f * a1);
    const float e0 = exp2f(a0);
    const float e1 = exp2f(a1);
    den += e0 + e1;
    fma_mix8(e0, u0, acc);
    fma_mix8(e1, u1, acc);
  }
  for (; i < deg; i += 8) {
    const unsigned s = (unsigned)row[i];
    float a = asp[s * 4u + hdu] + ad;
    a = fmaxf(a, 0.2f * a);
    const float ex = exp2f(a);
    den += ex;
    const uint4 u = *(const uint4*)(hby + (size_t)((s << 9) + cof));
    fma_mix8(ex, u, acc);
  }
  // reduce across the 8 slots (lane bits 3,4,5)
#pragma unroll
  for (int off = 8; off <= 32; off <<= 1) {
#pragma unroll
    for (int k = 0; k < 8; ++k) acc[k] += __shfl_xor(acc[k], off);
    den += __shfl_xor(den, off);
  }
  if (lane < 8) {
    const float inv = 1.f / den;
    float u[8];
#pragma unroll
    for (int k = 0; k < 8; ++k) u[k] = acc[k] * inv;
    if (mode == 0) {
      const float* bb = b + hd * CDIM + oc * 8;
      bf16x8 h8, l8;
#pragma unroll
      for (int k = 0; k < 8; ++k) {
        const float t0 = u[k] + bb[k];
        const float e = (t0 > 0.f) ? t0 : (__expf(t0) - 1.f);
        const short hi = f32_to_bf16_rne(e);
        h8[k] = hi;
        l8[k] = f32_to_bf16_rne(e - bf16_bits_to_f32(hi));
      }
      const size_t off = (size_t)n * HC + hd * CDIM + oc * 8;
      *(bf16x8*)(agg_hi + off) = h8;
      *(bf16x8*)(agg_lo + off) = l8;
    } else {
      float* op = outf + (size_t)n * HC + hd * CDIM + oc * 8;
      *(float4*)op = make_float4(u[0], u[1], u[2], u[3]);
      *(float4*)(op + 4) = make_float4(u[4], u[5], u[6], u[7]);
    }
  }
}

// ---- fused output head: out[n,:] = (mean_h agg[n,h,:] + b2) @ Wout + bout --
// (r7 form) one wave per node; lane = channel c; shfl butterfly.
__global__ __launch_bounds__(256) void final_fused_kernel(
    const float* __restrict__ agg, const float* __restrict__ b2,
    const float* __restrict__ Wout, const float* __restrict__ bout,
    float* __restrict__ out, int N) {
  const int n = blockIdx.x * 4 + (threadIdx.x >> 6);
  const int c = threadIdx.x & 63;
  if (n >= N) return;
  const float* ar = agg + (size_t)n * HC;
  const float m = 0.25f * (ar[c] + ar[c + 64] + ar[c + 128] + ar[c + 192]) +
                  b2[c];
  const float4* wr = (const float4*)(Wout + c * 16);
  const float4 w0 = wr[0], w1 = wr[1], w2 = wr[2], w3 = wr[3];
  float p[16] = {m * w0.x, m * w0.y, m * w0.z, m * w0.w,
                 m * w1.x, m * w1.y, m * w1.z, m * w1.w,
                 m * w2.x, m * w2.y, m * w2.z, m * w2.w,
                 m * w3.x, m * w3.y, m * w3.z, m * w3.w};
#pragma unroll
  for (int off = 1; off < 64; off <<= 1)
#pragma unroll
    for (int j = 0; j < 16; ++j) p[j] += __shfl_xor(p[j], off);
  if (c == 0) {
    float* op = out + (size_t)n * 16;
    *(float4*)op = make_float4(p[0] + bout[0], p[1] + bout[1],
                               p[2] + bout[2], p[3] + bout[3]);
    *(float4*)(op + 4) = make_float4(p[4] + bout[4], p[5] + bout[5],
                                     p[6] + bout[6], p[7] + bout[7]);
    *(float4*)(op + 8) = make_float4(p[8] + bout[8], p[9] + bout[9],
                                     p[10] + bout[10], p[11] + bout[11]);
    *(float4*)(op + 12) = make_float4(p[12] + bout[12], p[13] + bout[13],
                                      p[14] + bout[14], p[15] + bout[15]);
  }
}

extern "C" void kernel_launch(void* const* d_in, const int* in_sizes, int n_in,
                              void* d_out, int out_size, void* d_ws, size_t ws_size,
                              hipStream_t stream) {
  const float* x      = (const float*)d_in[0];
  const int*   eidx   = (const int*)d_in[1];
  const float* W1     = (const float*)d_in[2];
  const float* att_s1 = (const float*)d_in[3];
  const float* att_d1 = (const float*)d_in[4];
  const float* b1     = (const float*)d_in[5];
  const float* W2     = (const float*)d_in[6];
  const float* att_s2 = (const float*)d_in[7];
  const float* att_d2 = (const float*)d_in[8];
  const float* b2     = (const float*)d_in[9];
  const float* Wout   = (const float*)d_in[10];
  const float* bout   = (const float*)d_in[11];
  float* out          = (float*)d_out;

  const int N     = in_sizes[0] / 128;   // 20000
  const int E_raw = in_sizes[1] / 2;     // 640000
  const int Etot  = E_raw + N;           // + self loops
  const int* src = eidx;
  const int* dst = eidx + E_raw;

  // ---- workspace layout ----
  float* ws = (float*)d_ws;
  float* buf_agg = ws;                          // [N,256] f32 (agg2 out)
  float* buf_as  = buf_agg + (size_t)N * HC;    // [N,4]
  float* buf_ad  = buf_as + (size_t)N * HEADS;  // [N,4]
  __half* h16    = (__half*)(buf_ad + (size_t)N * HEADS);  // [N,256] f16
  int* cnt  = (int*)(h16 + (size_t)N * HC);     // [N*CNTS] padded counters
  int* ell  = cnt + (size_t)N * CNTS;           // [N*ELLW]
  uintptr_t wp = ((uintptr_t)(ell + (size_t)N * ELLW) + 15) & ~(uintptr_t)15;
  short* wt1_hi = (short*)wp;                   // [256][128]
  short* wt1_lo = wt1_hi + 256 * 128;
  short* wt2_hi = wt1_lo + 256 * 128;           // [256][256]
  short* wt2_lo = wt2_hi + 256 * 256;
  short* xh     = wt2_lo + 256 * 256;           // [N,128] x hi
  short* xl     = xh + (size_t)N * 128;         // [N,128] x lo
  short* agg_hi = xl + (size_t)N * 128;         // [N,256] agg1 hi
  short* agg_lo = agg_hi + (size_t)N * HC;      // [N,256] agg1 lo

  const dim3 blk(256);
  const int chunk_sz = (Etot + NCHUNK - 1) / NCHUNK;
  const int g_gemm = (N + 63) / 64;   // 313 gemm blocks (4 waves = heads)

  // ============ weight + x pack + cnt zero (one launch) ============
  pack_w12_kernel<<<PACKB, blk, 0, stream>>>(
      W1, wt1_hi, wt1_lo, W2, wt2_hi, wt2_lo, x, xh, xl, N * 128, cnt, N);

  // ======== Layer 1 GEMM ∥ ELL scatter (fused dispatch) ========
  gemm1_scatter_fused<<<g_gemm + NCHUNK * 8, blk, 0, stream>>>(
      xh, xl, wt1_hi, wt1_lo, h16, att_s1, att_d1, buf_as, buf_ad, N, 128,
      g_gemm, src, dst, cnt, ell, E_raw, Etot, chunk_sz);
  gat_aggregate_kernel<<<N, blk, 0, stream>>>(
      cnt, ell, h16, buf_as, buf_ad, b1, agg_hi, agg_lo, buf_agg, 0);

  // ================= Layer 2 =================
  gemm_mfma_split<<<g_gemm, blk, 0, stream>>>(
      agg_hi, agg_lo, wt2_hi, wt2_lo, h16, att_s2, att_d2, buf_as, buf_ad,
      N, 256);
  gat_aggregate_kernel<<<N, blk, 0, stream>>>(
      cnt, ell, h16, buf_as, buf_ad, b2, agg_hi, agg_lo, buf_agg, 1);

  // ================= Output head (mean + bias + Wout fused) =================
  final_fused_kernel<<<(N + 3) / 4, blk, 0, stream>>>(buf_agg, b2, Wout, bout,
                                                      out, N);
}

// Round 17
// 247.823 us; speedup vs baseline: 1.0364x; 1.0364x over previous
//
#include <hip/hip_runtime.h>
#include <hip/hip_bf16.h>
#include <hip/hip_fp16.h>

// ---------------------------------------------------------------------------
// 2-layer GAT (PyG GATConv semantics).
// Round 29 = r26 resubmitted byte-for-byte (best measured: 248.3us).
// Purpose: A/A disambiguation. r27 (pre-packed split-bf16 A) measured 256.9
// with BOTH aggregates slowed — including mode-1 whose code is identical to
// r26 — pointing at either a real L2-stream regression from split-A staging
// or container/clock variance (hbm_gbps -11% at same FETCH). If this run
// lands ~248, r27's delta was a true regression (stays abandoned); if ~256,
// variance is +-8us and the structure is at its measured plateau.
// Structure: pack(W1,W2,cnt) -> [gemm1 || XCD-bucketed ELL scatter] (fused
// dispatch) -> agg1 (head-affine, saddr+exp2) -> gemm2 -> agg2 -> final head.
// ---------------------------------------------------------------------------

#define HEADS 4
#define CDIM 64
#define HC 256   // HEADS*CDIM
#define ELLW 96  // ELL row stride (ints)
#define CNTS 16  // cnt stride in ints (64B line per counter)
#define NCHUNK 320  // edge chunks; scatter blocks = NCHUNK*8
#define LOG2E 1.44269504088896f

typedef __attribute__((ext_vector_type(8))) short bf16x8;   // 8 bf16 = 4 VGPR
typedef __attribute__((ext_vector_type(4))) float f32x4;    // MFMA acc

__device__ __forceinline__ short f32_to_bf16_rne(float v) {
  unsigned u = __float_as_uint(v);
  unsigned r = (u + 0x7FFFu + ((u >> 16) & 1u)) >> 16;
  return (short)r;
}
__device__ __forceinline__ float bf16_bits_to_f32(short s) {
  return __uint_as_float(((unsigned)(unsigned short)s) << 16);
}

// acc_lo += f16lo(reg)*ex ; acc_hi += f16hi(reg)*ex   (f32 accumulate)
__device__ __forceinline__ void fma_mix2(float& alo, float& ahi,
                                         unsigned reg, float ex) {
  asm("v_fma_mix_f32 %0, %2, %3, %0 op_sel:[0,0,0] op_sel_hi:[1,0,0]\n\t"
      "v_fma_mix_f32 %1, %2, %3, %1 op_sel:[1,0,0] op_sel_hi:[1,0,0]"
      : "+v"(alo), "+v"(ahi)
      : "v"(reg), "v"(ex));
}
__device__ __forceinline__ void fma_mix8(float ex, const uint4& u, float* acc) {
  fma_mix2(acc[0], acc[1], u.x, ex);
  fma_mix2(acc[2], acc[3], u.y, ex);
  fma_mix2(acc[4], acc[5], u.z, ex);
  fma_mix2(acc[6], acc[7], u.w, ex);
}

// ------ weight pack (W1+W2 one launch) + cnt-line zeroing (fused) ----------
__global__ __launch_bounds__(256) void pack_w12_kernel(
    const float* __restrict__ W1, short* __restrict__ W1h,
    short* __restrict__ W1l, const float* __restrict__ W2,
    short* __restrict__ W2h, short* __restrict__ W2l,
    int* __restrict__ cnt, int N) {
  const int i = blockIdx.x * 256 + threadIdx.x;
  if (i < N) cnt[i * CNTS] = 0;   // one counter per 64B line
  if (i < 128 * 256) {
    const int k = i >> 8, n = i & 255;
    const float v = W1[i];
    const short hi = f32_to_bf16_rne(v);
    W1h[n * 128 + k] = hi;
    W1l[n * 128 + k] = f32_to_bf16_rne(v - bf16_bits_to_f32(hi));
  } else {
    const int j = i - 128 * 256;
    if (j >= 256 * 256) return;
    const int k = j >> 8, n = j & 255;
    const float v = W2[j];
    const short hi = f32_to_bf16_rne(v);
    W2h[n * 256 + k] = hi;
    W2l[n * 256 + k] = f32_to_bf16_rne(v - bf16_bits_to_f32(hi));
  }
}

// ---------------- split-bf16 MFMA GEMM body: h = A[M,K] @ W[K,256] ---------
// (r19/r24 math) block = 256 thr (4 waves); wave = head. Epilogue stores
// attention scores pre-scaled by LOG2E.
__device__ __forceinline__ void gemm_body(
    short* As_hi, short* As_lo,
    const float* __restrict__ A, const short* __restrict__ Wt_hi,
    const short* __restrict__ Wt_lo, __half* __restrict__ h16,
    const float* __restrict__ att_s, const float* __restrict__ att_d,
    float* __restrict__ a_s, float* __restrict__ a_d, int M, int K, int bid) {
  const int t = threadIdx.x;
  const int wave = t >> 6;         // == head
  const int lane = t & 63;
  const int quad = lane >> 4;
  const int m16 = lane & 15;
  const int row0 = bid * 64;
  const int col0 = wave * 64;
  const int head = wave;

  f32x4 acc[4][4] = {};  // [mt][nt]

  for (int k0 = 0; k0 < K; k0 += 32) {
    if (k0) __syncthreads();
    {
      const int r = t >> 2, seg = t & 3;   // single-pass staging: 64x32
      const int gr = row0 + r;
      float vv[8] = {0.f, 0.f, 0.f, 0.f, 0.f, 0.f, 0.f, 0.f};
      if (gr < M) {
        const float* ap = A + (size_t)gr * K + k0 + seg * 8;
        const float4 v0 = *(const float4*)ap;
        const float4 v1 = *(const float4*)(ap + 4);
        vv[0] = v0.x; vv[1] = v0.y; vv[2] = v0.z; vv[3] = v0.w;
        vv[4] = v1.x; vv[5] = v1.y; vv[6] = v1.z; vv[7] = v1.w;
      }
      bf16x8 h8, l8;
#pragma unroll
      for (int j = 0; j < 8; ++j) {
        const short hi = f32_to_bf16_rne(vv[j]);
        h8[j] = hi;
        l8[j] = f32_to_bf16_rne(vv[j] - bf16_bits_to_f32(hi));
      }
      *(bf16x8*)(As_hi + r * 32 + seg * 8) = h8;
      *(bf16x8*)(As_lo + r * 32 + seg * 8) = l8;
    }
    bf16x8 b_hi[4], b_lo[4];
#pragma unroll
    for (int nt = 0; nt < 4; ++nt) {
      const size_t off = (size_t)(col0 + nt * 16 + m16) * K + k0 + quad * 8;
      b_hi[nt] = *(const bf16x8*)(Wt_hi + off);
      b_lo[nt] = *(const bf16x8*)(Wt_lo + off);
    }
    __syncthreads();
    bf16x8 a_hi[4], a_lo[4];
#pragma unroll
    for (int mt = 0; mt < 4; ++mt) {
      const int off = (mt * 16 + m16) * 32 + quad * 8;
      a_hi[mt] = *(const bf16x8*)(As_hi + off);
      a_lo[mt] = *(const bf16x8*)(As_lo + off);
    }
#pragma unroll
    for (int mt = 0; mt < 4; ++mt)
#pragma unroll
      for (int nt = 0; nt < 4; ++nt) {
        acc[mt][nt] = __builtin_amdgcn_mfma_f32_16x16x32_bf16(
            a_hi[mt], b_hi[nt], acc[mt][nt], 0, 0, 0);
        acc[mt][nt] = __builtin_amdgcn_mfma_f32_16x16x32_bf16(
            a_hi[mt], b_lo[nt], acc[mt][nt], 0, 0, 0);
        acc[mt][nt] = __builtin_amdgcn_mfma_f32_16x16x32_bf16(
            a_lo[mt], b_hi[nt], acc[mt][nt], 0, 0, 0);
      }
  }
  float sa[4], da[4];
#pragma unroll
  for (int nt = 0; nt < 4; ++nt) {
    sa[nt] = att_s[col0 + nt * 16 + m16];
    da[nt] = att_d[col0 + nt * 16 + m16];
  }
#pragma unroll
  for (int mt = 0; mt < 4; ++mt)
#pragma unroll
    for (int r = 0; r < 4; ++r) {
      const int gr = row0 + mt * 16 + quad * 4 + r;
      float ps = acc[mt][0][r] * sa[0] + acc[mt][1][r] * sa[1] +
                 acc[mt][2][r] * sa[2] + acc[mt][3][r] * sa[3];
      float pd = acc[mt][0][r] * da[0] + acc[mt][1][r] * da[1] +
                 acc[mt][2][r] * da[2] + acc[mt][3][r] * da[3];
#pragma unroll
      for (int off = 1; off <= 8; off <<= 1) {
        ps += __shfl_xor(ps, off);
        pd += __shfl_xor(pd, off);
      }
      if (gr < M) {
        if (m16 == 0) {
          a_s[gr * HEADS + head] = ps * LOG2E;   // pre-scaled for exp2
          a_d[gr * HEADS + head] = pd * LOG2E;
        }
#pragma unroll
        for (int nt = 0; nt < 4; ++nt)
          h16[(size_t)gr * HC + col0 + nt * 16 + m16] =
              __float2half(acc[mt][nt][r]);
      }
    }
}

// plain GEMM kernel (layer 2)
__global__ __launch_bounds__(256) void gemm_mfma_split(
    const float* __restrict__ A, const short* __restrict__ Wt_hi,
    const short* __restrict__ Wt_lo, __half* __restrict__ h16,
    const float* __restrict__ att_s, const float* __restrict__ att_d,
    float* __restrict__ a_s, float* __restrict__ a_d, int M, int K) {
  __shared__ alignas(16) short As_hi[64 * 32];
  __shared__ alignas(16) short As_lo[64 * 32];
  gemm_body(As_hi, As_lo, A, Wt_hi, Wt_lo, h16, att_s, att_d, a_s, a_d,
            M, K, blockIdx.x);
}

// ====== fused gemm1 + XCD-bucketed ELL scatter (independent ops) ===========
__global__ __launch_bounds__(256) void gemm1_scatter_fused(
    const float* __restrict__ A, const short* __restrict__ Wt_hi,
    const short* __restrict__ Wt_lo, __half* __restrict__ h16,
    const float* __restrict__ att_s, const float* __restrict__ att_d,
    float* __restrict__ a_s, float* __restrict__ a_d, int M, int K,
    int gblocks, const int* __restrict__ src, const int* __restrict__ dst,
    int* __restrict__ cnt, int* __restrict__ ell, int E_raw, int Etot,
    int chunk_sz) {
  __shared__ alignas(16) short As_hi[64 * 32];
  __shared__ alignas(16) short As_lo[64 * 32];
  const int bx = blockIdx.x;
  if (bx < gblocks) {
    gemm_body(As_hi, As_lo, A, Wt_hi, Wt_lo, h16, att_s, att_d, a_s, a_d,
              M, K, bx);
  } else {
    const int g = bx & 7;
    const int e0 = ((bx - gblocks) >> 3) * chunk_sz;
    int e1 = e0 + chunk_sz;
    if (e1 > Etot) e1 = Etot;
    for (int e = e0 + threadIdx.x; e < e1; e += 256) {
      const int d = (e < E_raw) ? dst[e] : (e - E_raw);
      if (((d >> 8) & 7) != g) continue;
      const int s = (e < E_raw) ? src[e] : (e - E_raw);
      const int pos = atomicAdd(&cnt[d * CNTS], 1);
      if (pos < ELLW) ell[d * ELLW + pos] = s;  // P(overflow) ~ 7e-18
    }
  }
}

// ================= fused softmax + aggregation (f16 gather) ================
// (r13/r23 loop structure; saddr addressing + exp2) grid = N blocks,
// head-affine (hd = bid&3, %8 XCD round-robin -> 2.56MB L2 slice).
// wave = node; lane: q = lane>>3 edge slot, oc = lane&7 channel octet.
// mode 0: out[n,c] = ELU(v + b[c]);  mode 1: out[n,c] = v.
__global__ __launch_bounds__(256) void gat_aggregate_kernel(
    const int* __restrict__ cnt, const int* __restrict__ ell,
    const __half* __restrict__ h16, const float* __restrict__ a_s,
    const float* __restrict__ a_d, const float* __restrict__ b,
    float* __restrict__ out, int mode) {
  const int bid = blockIdx.x;
  const int hd = bid & 3;
  const int n = (bid >> 2) * 4 + (threadIdx.x >> 6);
  const int lane = threadIdx.x & 63;
  const int q = lane >> 3;
  const int oc = lane & 7;
  const float ad = a_d[n * HEADS + hd];
  const int deg = cnt[n * CNTS];
  const int* __restrict__ row = ell + n * ELLW;
  const float* __restrict__ asp = a_s;                 // uniform base
  const unsigned hdu = (unsigned)hd;
  const char* __restrict__ hby = (const char*)h16;     // uniform base
  const unsigned cof = (unsigned)(hd * 128 + oc * 16); // per-lane voff const
  float acc[8] = {0.f, 0.f, 0.f, 0.f, 0.f, 0.f, 0.f, 0.f};
  float den = 0.f;
  int i = q;
  for (; i + 24 < deg; i += 32) {
    const unsigned s0 = (unsigned)row[i];
    const unsigned s1 = (unsigned)row[i + 8];
    const unsigned s2 = (unsigned)row[i + 16];
    const unsigned s3 = (unsigned)row[i + 24];
    const float as0 = asp[s0 * 4u + hdu];
    const float as1 = asp[s1 * 4u + hdu];
    const float as2 = asp[s2 * 4u + hdu];
    const float as3 = asp[s3 * 4u + hdu];
    const uint4 u0 = *(const uint4*)(hby + (size_t)((s0 << 9) + cof));
    const uint4 u1 = *(const uint4*)(hby + (size_t)((s1 << 9) + cof));
    const uint4 u2 = *(const uint4*)(hby + (size_t)((s2 << 9) + cof));
    const uint4 u3 = *(const uint4*)(hby + (size_t)((s3 << 9) + cof));
    float a0 = as0 + ad; a0 = fmaxf(a0, 0.2f * a0);
    float a1 = as1 + ad; a1 = fmaxf(a1, 0.2f * a1);
    float a2 = as2 + ad; a2 = fmaxf(a2, 0.2f * a2);
    float a3 = as3 + ad; a3 = fmaxf(a3, 0.2f * a3);
    const float e0 = exp2f(a0);
    const float e1 = exp2f(a1);
    const float e2 = exp2f(a2);
    const float e3 = exp2f(a3);
    den += e0 + e1 + e2 + e3;
    fma_mix8(e0, u0, acc);
    fma_mix8(e1, u1, acc);
    fma_mix8(e2, u2, acc);
    fma_mix8(e3, u3, acc);
  }
  for (; i + 8 < deg; i += 16) {
    const unsigned s0 = (unsigned)row[i];
    const unsigned s1 = (unsigned)row[i + 8];
    const float as0 = asp[s0 * 4u + hdu];
    const float as1 = asp[s1 * 4u + hdu];
    const uint4 u0 = *(const uint4*)(hby + (size_t)((s0 << 9) + cof));
    const uint4 u1 = *(const uint4*)(hby + (size_t)((s1 << 9) + cof));
    float a0 = as0 + ad; a0 = fmaxf(a0, 0.2f * a0);
    float a1 = as1 + ad; a1 = fmaxf(a1, 0.2f * a1);
    const float e0 = exp2f(a0);
    const float e1 = exp2f(a1);
    den += e0 + e1;
    fma_mix8(e0, u0, acc);
    fma_mix8(e1, u1, acc);
  }
  for (; i < deg; i += 8) {
    const unsigned s = (unsigned)row[i];
    float a = asp[s * 4u + hdu] + ad;
    a = fmaxf(a, 0.2f * a);
    const float ex = exp2f(a);
    den += ex;
    const uint4 u = *(const uint4*)(hby + (size_t)((s << 9) + cof));
    fma_mix8(ex, u, acc);
  }
  // reduce across the 8 slots (lane bits 3,4,5)
#pragma unroll
  for (int off = 8; off <= 32; off <<= 1) {
#pragma unroll
    for (int k = 0; k < 8; ++k) acc[k] += __shfl_xor(acc[k], off);
    den += __shfl_xor(den, off);
  }
  if (lane < 8) {
    const float inv = 1.f / den;
    float u[8];
#pragma unroll
    for (int k = 0; k < 8; ++k) u[k] = acc[k] * inv;
    if (mode == 0) {
      const float* bb = b + hd * CDIM + oc * 8;
#pragma unroll
      for (int k = 0; k < 8; ++k) {
        const float t0 = u[k] + bb[k];
        u[k] = (t0 > 0.f) ? t0 : (__expf(t0) - 1.f);
      }
    }
    float* op = out + (size_t)n * HC + hd * CDIM + oc * 8;
    *(float4*)op = make_float4(u[0], u[1], u[2], u[3]);
    *(float4*)(op + 4) = make_float4(u[4], u[5], u[6], u[7]);
  }
}

// ---- fused output head: out[n,:] = (mean_h agg[n,h,:] + b2) @ Wout + bout --
// (r7 form) one wave per node; lane = channel c; shfl butterfly.
__global__ __launch_bounds__(256) void final_fused_kernel(
    const float* __restrict__ agg, const float* __restrict__ b2,
    const float* __restrict__ Wout, const float* __restrict__ bout,
    float* __restrict__ out, int N) {
  const int n = blockIdx.x * 4 + (threadIdx.x >> 6);
  const int c = threadIdx.x & 63;
  if (n >= N) return;
  const float* ar = agg + (size_t)n * HC;
  const float m = 0.25f * (ar[c] + ar[c + 64] + ar[c + 128] + ar[c + 192]) +
                  b2[c];
  const float4* wr = (const float4*)(Wout + c * 16);
  const float4 w0 = wr[0], w1 = wr[1], w2 = wr[2], w3 = wr[3];
  float p[16] = {m * w0.x, m * w0.y, m * w0.z, m * w0.w,
                 m * w1.x, m * w1.y, m * w1.z, m * w1.w,
                 m * w2.x, m * w2.y, m * w2.z, m * w2.w,
                 m * w3.x, m * w3.y, m * w3.z, m * w3.w};
#pragma unroll
  for (int off = 1; off < 64; off <<= 1)
#pragma unroll
    for (int j = 0; j < 16; ++j) p[j] += __shfl_xor(p[j], off);
  if (c == 0) {
    float* op = out + (size_t)n * 16;
    *(float4*)op = make_float4(p[0] + bout[0], p[1] + bout[1],
                               p[2] + bout[2], p[3] + bout[3]);
    *(float4*)(op + 4) = make_float4(p[4] + bout[4], p[5] + bout[5],
                                     p[6] + bout[6], p[7] + bout[7]);
    *(float4*)(op + 8) = make_float4(p[8] + bout[8], p[9] + bout[9],
                                     p[10] + bout[10], p[11] + bout[11]);
    *(float4*)(op + 12) = make_float4(p[12] + bout[12], p[13] + bout[13],
                                      p[14] + bout[14], p[15] + bout[15]);
  }
}

extern "C" void kernel_launch(void* const* d_in, const int* in_sizes, int n_in,
                              void* d_out, int out_size, void* d_ws, size_t ws_size,
                              hipStream_t stream) {
  const float* x      = (const float*)d_in[0];
  const int*   eidx   = (const int*)d_in[1];
  const float* W1     = (const float*)d_in[2];
  const float* att_s1 = (const float*)d_in[3];
  const float* att_d1 = (const float*)d_in[4];
  const float* b1     = (const float*)d_in[5];
  const float* W2     = (const float*)d_in[6];
  const float* att_s2 = (const float*)d_in[7];
  const float* att_d2 = (const float*)d_in[8];
  const float* b2     = (const float*)d_in[9];
  const float* Wout   = (const float*)d_in[10];
  const float* bout   = (const float*)d_in[11];
  float* out          = (float*)d_out;

  const int N     = in_sizes[0] / 128;   // 20000
  const int E_raw = in_sizes[1] / 2;     // 640000
  const int Etot  = E_raw + N;           // + self loops
  const int* src = eidx;
  const int* dst = eidx + E_raw;

  // ---- workspace layout (r23 form) ----
  float* ws = (float*)d_ws;
  float* buf_agg = ws;                          // [N,256] agg1/ELU out, agg2
  float* buf_as  = buf_agg + (size_t)N * HC;    // [N,4]
  float* buf_ad  = buf_as + (size_t)N * HEADS;  // [N,4]
  __half* h16    = (__half*)(buf_ad + (size_t)N * HEADS);  // [N,256] f16
  int* cnt  = (int*)(h16 + (size_t)N * HC);     // [N*CNTS] padded counters
  int* ell  = cnt + (size_t)N * CNTS;           // [N*ELLW]
  uintptr_t wp = ((uintptr_t)(ell + (size_t)N * ELLW) + 15) & ~(uintptr_t)15;
  short* wt1_hi = (short*)wp;                   // [256][128]
  short* wt1_lo = wt1_hi + 256 * 128;
  short* wt2_hi = wt1_lo + 256 * 128;           // [256][256]
  short* wt2_lo = wt2_hi + 256 * 256;

  const dim3 blk(256);
  const int chunk_sz = (Etot + NCHUNK - 1) / NCHUNK;
  const int g_gemm = (N + 63) / 64;   // 313 gemm blocks (4 waves = heads)

  // ================= weight pack + cnt zero =================
  pack_w12_kernel<<<(384 * 256 + 255) / 256, blk, 0, stream>>>(
      W1, wt1_hi, wt1_lo, W2, wt2_hi, wt2_lo, cnt, N);

  // ======== Layer 1 GEMM ∥ ELL scatter (fused dispatch) ========
  gemm1_scatter_fused<<<g_gemm + NCHUNK * 8, blk, 0, stream>>>(
      x, wt1_hi, wt1_lo, h16, att_s1, att_d1, buf_as, buf_ad, N, 128,
      g_gemm, src, dst, cnt, ell, E_raw, Etot, chunk_sz);
  gat_aggregate_kernel<<<N, blk, 0, stream>>>(cnt, ell, h16, buf_as,
                                              buf_ad, b1, buf_agg, 0);

  // ================= Layer 2 =================
  gemm_mfma_split<<<g_gemm, blk, 0, stream>>>(
      buf_agg, wt2_hi, wt2_lo, h16, att_s2, att_d2, buf_as, buf_ad, N, 256);
  gat_aggregate_kernel<<<N, blk, 0, stream>>>(cnt, ell, h16, buf_as,
                                              buf_ad, b2, buf_agg, 1);

  // ================= Output head (mean + bias + Wout fused) =================
  final_fused_kernel<<<(N + 3) / 4, blk, 0, stream>>>(buf_agg, b2, Wout, bout,
                                                      out, N);
}